// Round 1
// baseline (56747.968 us; speedup 1.0000x reference)
//
#include <hip/hip_runtime.h>
#include <math.h>

// Problem constants (fixed by setup_inputs)
#define TT  256   // scan steps
#define BB  32    // batch
#define EE  1024  // embed dim
#define MM  4096  // mlp dim
#define VV  4096  // vocab
#define BE  (BB*EE)      // 32768
#define NROWS (TT*BB)    // 8192
#define EPSF 1.1920929e-07f

__global__ void k_zero(float* __restrict__ p, int n) {
  int i = blockIdx.x * 256 + threadIdx.x;
  if (i < n) p[i] = 0.f;
}

__global__ void k_init(const int* __restrict__ tokens,
                       const float* __restrict__ embw,
                       float* __restrict__ inp0) {
  int b = blockIdx.x;
  int tok = tokens[b * TT];  // tokens[b][0]
  for (int e = threadIdx.x; e < EE; e += 256)
    inp0[b * EE + e] = embw[tok * EE + e];
}

// y = silu(rmsnorm(h, bnw) @ W^T + bias), W:[4096][1024]
// Fused: Σh^2 accumulated during staging (rinv applied to the linear accumulator
// at the end). Block 0 additionally writes initDst = h + initBias (+ initAdd):
// the pre-initialized accumulation target for the following k_fc2 atomics.
__global__ __launch_bounds__(256)
void k_fc1(const float* __restrict__ h,
           const float* __restrict__ bnw,
           const float* __restrict__ W,
           const float* __restrict__ bias,
           float* __restrict__ yout,
           float* __restrict__ initDst,
           const float* __restrict__ initAdd,
           const float* __restrict__ initBias) {
  __shared__ __align__(16) float Hs[32][68];
  __shared__ __align__(16) float Ws[8][68];
  __shared__ float ssrow[32];
  const int tid = threadIdx.x;
  const int col0 = blockIdx.x * 8;
  const int c = tid & 7;
  const int b = tid >> 3;
  const bool writer = (blockIdx.x == 0);
  float acc = 0.f;
  float ssl[8];
#pragma unroll
  for (int j = 0; j < 8; ++j) ssl[j] = 0.f;

  for (int kc = 0; kc < EE; kc += 64) {
#pragma unroll
    for (int j = 0; j < 8; ++j) {
      int i = tid + j * 256;
      int bb = i >> 6, k = i & 63;
      float v = h[bb * EE + kc + k];
      ssl[j] += v * v;
      Hs[bb][k] = v * bnw[kc + k];
      if (writer) {
        float d = v + initBias[kc + k];
        if (initAdd) d += initAdd[bb * EE + kc + k];
        initDst[bb * EE + kc + k] = d;
      }
    }
#pragma unroll
    for (int j = 0; j < 2; ++j) {
      int i = tid + j * 256;
      int cc = i >> 6, k = i & 63;
      Ws[cc][k] = W[(col0 + cc) * EE + kc + k];
    }
    __syncthreads();
#pragma unroll
    for (int k = 0; k < 64; k += 4) {
      float4 w4 = *(const float4*)&Ws[c][k];
      float4 h4 = *(const float4*)&Hs[b][k];
      acc += h4.x * w4.x + h4.y * w4.y + h4.z * w4.z + h4.w * w4.w;
    }
    __syncthreads();
  }
  // wave wv staged rows {wv+4j}; reduce Σh^2 across the 64 lanes of each wave
  const int wv = tid >> 6;
#pragma unroll
  for (int j = 0; j < 8; ++j) {
    float v = ssl[j];
#pragma unroll
    for (int off = 32; off > 0; off >>= 1) v += __shfl_xor(v, off);
    if ((tid & 63) == 0) ssrow[wv + 4 * j] = v;
  }
  __syncthreads();
  float rinv = rsqrtf(ssrow[b] * (1.f / EE) + EPSF);
  float z = acc * rinv + bias[col0 + c];
  yout[b * MM + col0 + c] = z / (1.f + expf(-z));  // silu
}

// dest[b][e] += y[b][:] . W2[e][:]  over this block's K-slice (K split 8 ways).
// dest pre-initialized with (h + bias (+ inp)) by the preceding k_fc1.
__global__ __launch_bounds__(256)
void k_fc2(const float* __restrict__ y,
           const float* __restrict__ W2,
           float* __restrict__ dest) {
  __shared__ __align__(16) float Ys[32][68];
  __shared__ __align__(16) float Ws[16][68];
  const int tid = threadIdx.x;
  const int cg = blockIdx.x & 63;   // 64 col groups * 16 cols
  const int ks = blockIdx.x >> 6;   // 8 K-slices * 512
  const int col0 = cg * 16;
  const int c = tid & 15;
  const int bq = tid >> 4;          // 0..15
  float acc0 = 0.f, acc1 = 0.f;
  const int kend = ks * 512 + 512;
  for (int kc = ks * 512; kc < kend; kc += 64) {
#pragma unroll
    for (int j = 0; j < 8; ++j) {
      int i = tid + j * 256;
      int bb = i >> 6, k = i & 63;
      Ys[bb][k] = y[bb * MM + kc + k];
    }
#pragma unroll
    for (int j = 0; j < 4; ++j) {
      int i = tid + j * 256;
      int cc = i >> 6, k = i & 63;
      Ws[cc][k] = W2[(col0 + cc) * MM + kc + k];
    }
    __syncthreads();
#pragma unroll
    for (int k = 0; k < 64; k += 4) {
      float4 w4 = *(const float4*)&Ws[c][k];
      float4 a4 = *(const float4*)&Ys[bq][k];
      float4 b4 = *(const float4*)&Ys[bq + 16][k];
      acc0 += a4.x * w4.x + a4.y * w4.y + a4.z * w4.z + a4.w * w4.w;
      acc1 += b4.x * w4.x + b4.y * w4.y + b4.z * w4.z + b4.w * w4.w;
    }
    __syncthreads();
  }
  atomicAdd(&dest[bq * EE + col0 + c], acc0);
  atomicAdd(&dest[(bq + 16) * EE + col0 + c], acc1);
}

// x = rmsnorm(s, nw); nxt = x @ Wn^T + nb; carry: inp_next = emb[tok_{t+1}] + nxt.
// Self-normalizing like k_fc1; block 0 also persists ss_s (raw Σs^2) for phase 2.
__global__ __launch_bounds__(256)
void k_nxt(const float* __restrict__ s,
           const float* __restrict__ nw,
           const float* __restrict__ Wn,
           const float* __restrict__ nb,
           float* __restrict__ nxt_out,
           float* __restrict__ ss_out,
           const int* __restrict__ tokens,
           const float* __restrict__ embw,
           float* __restrict__ inp_next,
           int tnext) {
  __shared__ __align__(16) float Xs[32][68];
  __shared__ __align__(16) float Ws[8][68];
  __shared__ float ssrow[32];
  const int tid = threadIdx.x;
  const int col0 = blockIdx.x * 8;
  const int c = tid & 7;
  const int b = tid >> 3;
  float acc = 0.f;
  float ssl[8];
#pragma unroll
  for (int j = 0; j < 8; ++j) ssl[j] = 0.f;
  for (int kc = 0; kc < EE; kc += 64) {
#pragma unroll
    for (int j = 0; j < 8; ++j) {
      int i = tid + j * 256;
      int bb = i >> 6, k = i & 63;
      float v = s[bb * EE + kc + k];
      ssl[j] += v * v;
      Xs[bb][k] = v * nw[kc + k];
    }
#pragma unroll
    for (int j = 0; j < 2; ++j) {
      int i = tid + j * 256;
      int cc = i >> 6, k = i & 63;
      Ws[cc][k] = Wn[(col0 + cc) * EE + kc + k];
    }
    __syncthreads();
#pragma unroll
    for (int k = 0; k < 64; k += 4) {
      float4 w4 = *(const float4*)&Ws[c][k];
      float4 h4 = *(const float4*)&Xs[b][k];
      acc += h4.x * w4.x + h4.y * w4.y + h4.z * w4.z + h4.w * w4.w;
    }
    __syncthreads();
  }
  const int wv = tid >> 6;
#pragma unroll
  for (int j = 0; j < 8; ++j) {
    float v = ssl[j];
#pragma unroll
    for (int off = 32; off > 0; off >>= 1) v += __shfl_xor(v, off);
    if ((tid & 63) == 0) {
      ssrow[wv + 4 * j] = v;
      if (blockIdx.x == 0) ss_out[wv + 4 * j] = v;
    }
  }
  __syncthreads();
  float rinv = rsqrtf(ssrow[b] * (1.f / EE) + EPSF);
  float nv = acc * rinv + nb[col0 + c];
  nxt_out[b * EE + col0 + c] = nv;
  if (inp_next) {
    int tok = tokens[b * TT + tnext];
    inp_next[b * EE + col0 + c] = embw[tok * EE + col0 + c] + nv;
  }
}

// cur_emb = rmsnorm(s, nw) @ cur_w^T + cur_b over all 8192 rows; fused aux.
__global__ __launch_bounds__(256)
void k_curemb(const float* __restrict__ s_all,
              const float* __restrict__ ss_s,
              const float* __restrict__ nw,
              const float* __restrict__ Wc,
              const float* __restrict__ cb,
              const float* __restrict__ inp_all,
              float* __restrict__ cur_out,
              float* __restrict__ aux_accum) {
  __shared__ __align__(16) float As[16][68];
  __shared__ __align__(16) float Bs[16][68];
  __shared__ float rr[64];
  __shared__ float wred[4];
  const int tid = threadIdx.x;
  const int rt = blockIdx.x & 127;
  const int ct = blockIdx.x >> 7;
  const int row0 = rt * 64, col0 = ct * 64;
  if (tid < 64) rr[tid] = rsqrtf(ss_s[row0 + tid] * (1.f / EE) + EPSF);
  __syncthreads();
  float acc[4][4];
#pragma unroll
  for (int i = 0; i < 4; ++i)
#pragma unroll
    for (int j = 0; j < 4; ++j) acc[i][j] = 0.f;
  const int tx = tid & 15, ty = tid >> 4;
  for (int kc = 0; kc < EE; kc += 16) {
#pragma unroll
    for (int j = 0; j < 4; ++j) {
      int i = tid + j * 256;
      int k = i & 15, m = i >> 4;
      As[k][m] = s_all[(row0 + m) * EE + kc + k] * rr[m] * nw[kc + k];
      Bs[k][m] = Wc[(col0 + m) * EE + kc + k];
    }
    __syncthreads();
#pragma unroll
    for (int k = 0; k < 16; ++k) {
      float4 a4 = *(const float4*)&As[k][tx * 4];
      float4 b4 = *(const float4*)&Bs[k][ty * 4];
      acc[0][0] += a4.x*b4.x; acc[0][1] += a4.x*b4.y; acc[0][2] += a4.x*b4.z; acc[0][3] += a4.x*b4.w;
      acc[1][0] += a4.y*b4.x; acc[1][1] += a4.y*b4.y; acc[1][2] += a4.y*b4.z; acc[1][3] += a4.y*b4.w;
      acc[2][0] += a4.z*b4.x; acc[2][1] += a4.z*b4.y; acc[2][2] += a4.z*b4.z; acc[2][3] += a4.z*b4.w;
      acc[3][0] += a4.w*b4.x; acc[3][1] += a4.w*b4.y; acc[3][2] += a4.w*b4.z; acc[3][3] += a4.w*b4.w;
    }
    __syncthreads();
  }
  float auxp = 0.f;
#pragma unroll
  for (int i = 0; i < 4; ++i) {
    int r = row0 + tx * 4 + i;
#pragma unroll
    for (int j = 0; j < 4; ++j) {
      int col = col0 + ty * 4 + j;
      float v = acc[i][j] + cb[col];
      cur_out[r * EE + col] = v;
      float d = v - inp_all[r * EE + col];
      auxp += d * d;
    }
  }
#pragma unroll
  for (int off = 32; off > 0; off >>= 1) auxp += __shfl_xor(auxp, off);
  if ((tid & 63) == 0) wred[tid >> 6] = auxp;
  __syncthreads();
  if (tid == 0) atomicAdd(aux_accum, wred[0] + wred[1] + wred[2] + wred[3]);
}

// logits = A @ emb_w^T; fused Σexp row-sums + target-logit pick; optional
// permuted [B][T][V] store. Logits are O(0.01) so exp without max-shift is safe.
__global__ __launch_bounds__(256)
void k_logits(const float* __restrict__ A,
              const float* __restrict__ embw,
              const int* __restrict__ idxs,
              float* __restrict__ rowsum,
              float* __restrict__ lidx,
              float* __restrict__ store) {
  __shared__ __align__(16) float As[16][68];
  __shared__ __align__(16) float Bs[16][68];
  __shared__ float rowpart[64];
  const int tid = threadIdx.x;
  const int rt = blockIdx.x & 127;
  const int ct = blockIdx.x >> 7;
  const int row0 = rt * 64, col0 = ct * 64;
  float acc[4][4];
#pragma unroll
  for (int i = 0; i < 4; ++i)
#pragma unroll
    for (int j = 0; j < 4; ++j) acc[i][j] = 0.f;
  const int tx = tid & 15, ty = tid >> 4;
  for (int kc = 0; kc < EE; kc += 16) {
#pragma unroll
    for (int j = 0; j < 4; ++j) {
      int i = tid + j * 256;
      int k = i & 15, m = i >> 4;
      As[k][m] = A[(row0 + m) * EE + kc + k];
      Bs[k][m] = embw[(col0 + m) * EE + kc + k];
    }
    __syncthreads();
#pragma unroll
    for (int k = 0; k < 16; ++k) {
      float4 a4 = *(const float4*)&As[k][tx * 4];
      float4 b4 = *(const float4*)&Bs[k][ty * 4];
      acc[0][0] += a4.x*b4.x; acc[0][1] += a4.x*b4.y; acc[0][2] += a4.x*b4.z; acc[0][3] += a4.x*b4.w;
      acc[1][0] += a4.y*b4.x; acc[1][1] += a4.y*b4.y; acc[1][2] += a4.y*b4.z; acc[1][3] += a4.y*b4.w;
      acc[2][0] += a4.z*b4.x; acc[2][1] += a4.z*b4.y; acc[2][2] += a4.z*b4.z; acc[2][3] += a4.z*b4.w;
      acc[3][0] += a4.w*b4.x; acc[3][1] += a4.w*b4.y; acc[3][2] += a4.w*b4.z; acc[3][3] += a4.w*b4.w;
    }
    __syncthreads();
  }
  if (tid < 64) rowpart[tid] = 0.f;
  __syncthreads();
#pragma unroll
  for (int i = 0; i < 4; ++i) {
    int r = row0 + tx * 4 + i;
    int t = r >> 5, bb = r & 31;  // r = t*B + b
    int idx = idxs[bb * TT + t];
    float e0 = expf(acc[i][0]);
    float e1 = expf(acc[i][1]);
    float e2 = expf(acc[i][2]);
    float e3 = expf(acc[i][3]);
    atomicAdd(&rowpart[tx * 4 + i], e0 + e1 + e2 + e3);
    int cbase = col0 + ty * 4;
#pragma unroll
    for (int j = 0; j < 4; ++j)
      if (cbase + j == idx) lidx[r] = acc[i][j];
    if (store) {
      float4 o = make_float4(acc[i][0], acc[i][1], acc[i][2], acc[i][3]);
      *(float4*)(store + ((size_t)bb * TT + t) * VV + cbase) = o;
    }
  }
  __syncthreads();
  if (tid < 64) atomicAdd(&rowsum[row0 + tid], rowpart[tid]);
}

__global__ void k_final(const float* __restrict__ rs_cur,
                        const float* __restrict__ rs_nxt,
                        const float* __restrict__ ltok,
                        const float* __restrict__ ltgt,
                        const float* __restrict__ aux_accum,
                        float* __restrict__ out) {
  float p = 0.f;
  for (int r = threadIdx.x; r < NROWS; r += 256)
    p += (ltok[r] - logf(rs_cur[r])) + (ltgt[r] - logf(rs_nxt[r]));
#pragma unroll
  for (int off = 32; off > 0; off >>= 1) p += __shfl_xor(p, off);
  __shared__ float w[4];
  if ((threadIdx.x & 63) == 0) w[threadIdx.x >> 6] = p;
  __syncthreads();
  if (threadIdx.x == 0) {
    float tot = w[0] + w[1] + w[2] + w[3];
    out[0] = -tot / (2.f * (float)NROWS);                  // mean CE
    out[1] = aux_accum[0] * (1.f / ((float)NROWS * EE));   // mean aux
  }
}

extern "C" void kernel_launch(void* const* d_in, const int* in_sizes, int n_in,
                              void* d_out, int out_size, void* d_ws, size_t ws_size,
                              hipStream_t stream) {
  (void)in_sizes; (void)n_in; (void)out_size; (void)ws_size;
  const int*   tokens  = (const int*)d_in[0];
  const int*   targets = (const int*)d_in[1];
  const float* embw    = (const float*)d_in[2];
  const float* bnw     = (const float*)d_in[3];
  const float* fc1w    = (const float*)d_in[4];
  const float* fc1b    = (const float*)d_in[5];
  const float* fc2w    = (const float*)d_in[6];
  const float* fc2b    = (const float*)d_in[7];
  const float* nw      = (const float*)d_in[8];
  const float* curw    = (const float*)d_in[9];
  const float* curb    = (const float*)d_in[10];
  const float* nxtw    = (const float*)d_in[11];
  const float* nxtb    = (const float*)d_in[12];
  float* out = (float*)d_out;

  // d_out (33.55M floats) doubles as scratch for the first three [8192][1024]
  // activations; the final logits GEMM (reads only nxt_all from ws) overwrites
  // all of it with the real output.
  float* cur_all = out;
  float* s_all   = out + (size_t)NROWS * EE;
  float* inp_all = out + 2 * (size_t)NROWS * EE;

  float* ws      = (float*)d_ws;
  float* nxt_all = ws;
  float* hbuf    = nxt_all + (size_t)NROWS * EE;
  float* ybuf    = hbuf + BE;
  float* ss_s    = ybuf + BB * MM;
  float* rs_cur  = ss_s + NROWS;
  float* rs_nxt  = rs_cur + NROWS;
  float* auxac   = rs_nxt + NROWS;
  float* ltok    = auxac + 1;
  float* ltgt    = ltok + NROWS;

  // zero the accumulators (rs_cur, rs_nxt, aux) — contiguous
  k_zero<<<(2 * NROWS + 1 + 255) / 256, 256, 0, stream>>>(rs_cur, 2 * NROWS + 1);
  k_init<<<32, 256, 0, stream>>>(tokens, embw, inp_all);

  for (int t = 0; t < TT; ++t) {
    const float* inp = inp_all + (size_t)t * BE;
    float* s = s_all + (size_t)t * BE;
    // layer 0: h starts as inp; fc1a's block0 seeds hbuf = inp + fc2_b[0]
    k_fc1<<<512, 256, 0, stream>>>(inp, bnw, fc1w, fc1b, ybuf,
                                   hbuf, nullptr, fc2b);
    k_fc2<<<512, 256, 0, stream>>>(ybuf, fc2w, hbuf);
    // layer 1: h = hbuf; fc1b's block0 seeds s = inp + hbuf + fc2_b[1]
    k_fc1<<<512, 256, 0, stream>>>(hbuf, bnw + EE, fc1w + (size_t)MM * EE,
                                   fc1b + MM, ybuf, s, inp, fc2b + EE);
    k_fc2<<<512, 256, 0, stream>>>(ybuf, fc2w + (size_t)EE * MM, s);
    k_nxt<<<128, 256, 0, stream>>>(s, nw, nxtw, nxtb,
                                   nxt_all + (size_t)t * BE, ss_s + t * BB,
                                   tokens, embw,
                                   (t + 1 < TT) ? inp_all + (size_t)(t + 1) * BE : nullptr,
                                   t + 1);
  }

  k_curemb<<<2048, 256, 0, stream>>>(s_all, ss_s, nw, curw, curb, inp_all,
                                     cur_all, auxac);
  k_logits<<<8192, 256, 0, stream>>>(cur_all, embw, tokens, rs_cur, ltok, nullptr);
  k_logits<<<8192, 256, 0, stream>>>(nxt_all, embw, targets, rs_nxt, ltgt, out);
  k_final<<<1, 256, 0, stream>>>(rs_cur, rs_nxt, ltok, ltgt, auxac,
                                 out + (size_t)NROWS * VV);
}